// Round 8
// baseline (98.324 us; speedup 1.0000x reference)
//
#include <hip/hip_runtime.h>

#define BLOCK 256
#define LOG_2PI_F 1.8378770664093453f

// ws layout (float offsets):
//   0..7   : stats: [2] ld_sum0 [3] ld_sum1 [4] cnt0 [5] cnt1
//   16     : p_tab [2*D]   (= 0.5*exp(-2*lsd))
//   16+2D  : q_tab [2*D]   (= 2*p*mu)
//   PART0  : partials [2(z)][gyR][2][Dp]   (plane 0 = sumAll, 1 = sumC1), Dp = D
//
// out layout: [0] prior | [1,1+2D) mus | [1+2D,1+4D) lsds |
//             [1+4D,1+4D+N) logp | [1+4D+N, +2) log_p_total

__device__ __forceinline__ void acc4(float4& s, const float4 d) {
    s.x += d.x; s.y += d.y; s.z += d.z; s.w += d.w;
}
__device__ __forceinline__ void fma4(float4& s, const float4 d, const float w) {
    s.x = fmaf(d.x, w, s.x); s.y = fmaf(d.y, w, s.y);
    s.z = fmaf(d.z, w, s.z); s.w = fmaf(d.w, w, s.w);
}

// forced-in-flight 16B global load: issue now, wait later (HK pattern)
__device__ __forceinline__ float4 gload16(const float4* p) {
    float4 d;
    asm volatile("global_load_dwordx4 %0, %1, off" : "=v"(d) : "v"(p));
    return d;
}

// shared stats helper: counts + per-class logdet sums (run by one block)
__device__ void do_stats(const int* __restrict__ target,
                         const float* __restrict__ logdet,
                         float* __restrict__ stats, int N)
{
    const int tid = threadIdx.x;
    float ldA = 0.f, ld1 = 0.f;
    int   c1  = 0;
    if ((N & 3) == 0) {
        const int4*   t4 = reinterpret_cast<const int4*>(target);
        const float4* l4 = reinterpret_cast<const float4*>(logdet);
        for (int i = tid; i < (N >> 2); i += BLOCK) {
            const int4   t = t4[i];
            const float4 v = l4[i];
            ldA += v.x + v.y + v.z + v.w;
            if (t.x) { c1++; ld1 += v.x; }
            if (t.y) { c1++; ld1 += v.y; }
            if (t.z) { c1++; ld1 += v.z; }
            if (t.w) { c1++; ld1 += v.w; }
        }
    } else {
        for (int n = tid; n < N; n += BLOCK) {
            const float v = logdet[n];
            ldA += v;
            if (target[n]) { c1++; ld1 += v; }
        }
    }
    __shared__ float sB[BLOCK], sC[BLOCK];
    __shared__ int   sI[BLOCK];
    sB[tid] = ldA; sC[tid] = ld1; sI[tid] = c1;
    __syncthreads();
    for (int off = BLOCK / 2; off > 0; off >>= 1) {
        if (tid < off) {
            sB[tid] += sB[tid + off];
            sC[tid] += sC[tid + off];
            sI[tid] += sI[tid + off];
        }
        __syncthreads();
    }
    if (tid == 0) {
        stats[2] = sB[0] - sC[0];          // ld_sum0
        stats[3] = sC[0];                  // ld_sum1
        stats[4] = (float)(N - sI[0]);     // cnt0
        stats[5] = (float)sI[0];           // cnt1
    }
}

// fast path (D == 3072): block streams full row width; 12 loads in flight
__global__ __launch_bounds__(BLOCK, 4) void k_colsum3(
    const float* __restrict__ mean,
    const float* __restrict__ log_sd,
    const int*   __restrict__ target,
    const float* __restrict__ logdet,
    float* __restrict__ partials,
    float* __restrict__ stats,
    int N, int rowsPerBlk, int gyR)
{
    const int tid = threadIdx.x;
    const int by  = blockIdx.x;
    const int z   = blockIdx.y;
    const int D4  = 768;                        // 3072 / 4
    const int rowBase = by * rowsPerBlk;
    int rEnd = rowsPerBlk;
    if (rowBase + rEnd > N) rEnd = N - rowBase;
    if (rEnd < 0) rEnd = 0;

    const float4* src4 =
        reinterpret_cast<const float4*>(z == 0 ? mean : log_sd);
    const float4* p   = src4 + (size_t)rowBase * D4 + tid;
    const int*    tgt = target + rowBase;

    float4 sA0 = make_float4(0.f,0.f,0.f,0.f);
    float4 sA1 = make_float4(0.f,0.f,0.f,0.f);
    float4 sA2 = make_float4(0.f,0.f,0.f,0.f);
    float4 s10 = make_float4(0.f,0.f,0.f,0.f);
    float4 s11 = make_float4(0.f,0.f,0.f,0.f);
    float4 s12 = make_float4(0.f,0.f,0.f,0.f);

    int r = 0;
    for (; r + 4 <= rEnd; r += 4) {
        // per-step weights: one uniform int4 load
        const int4 tv = *reinterpret_cast<const int4*>(tgt + r);
        const float4* r0 = p + (size_t)r * D4;
        const float4* r1 = r0 + D4;
        const float4* r2 = r1 + D4;
        const float4* r3 = r2 + D4;
        // issue 12 independent 16B loads; all stay in flight (volatile order)
        const float4 a0 = gload16(r0);
        const float4 a1 = gload16(r0 + 256);
        const float4 a2 = gload16(r0 + 512);
        const float4 b0 = gload16(r1);
        const float4 b1 = gload16(r1 + 256);
        const float4 b2 = gload16(r1 + 512);
        const float4 c0 = gload16(r2);
        const float4 c1 = gload16(r2 + 256);
        const float4 c2 = gload16(r2 + 512);
        const float4 d0 = gload16(r3);
        const float4 d1 = gload16(r3 + 256);
        const float4 d2 = gload16(r3 + 512);
        asm volatile("s_waitcnt vmcnt(0)" ::: "memory");
        __builtin_amdgcn_sched_barrier(0);      // rule #18: keep consumers below
        const float w0 = tv.x ? 1.f : 0.f;
        const float w1 = tv.y ? 1.f : 0.f;
        const float w2 = tv.z ? 1.f : 0.f;
        const float w3 = tv.w ? 1.f : 0.f;
        acc4(sA0, a0); fma4(s10, a0, w0);
        acc4(sA1, a1); fma4(s11, a1, w0);
        acc4(sA2, a2); fma4(s12, a2, w0);
        acc4(sA0, b0); fma4(s10, b0, w1);
        acc4(sA1, b1); fma4(s11, b1, w1);
        acc4(sA2, b2); fma4(s12, b2, w1);
        acc4(sA0, c0); fma4(s10, c0, w2);
        acc4(sA1, c1); fma4(s11, c1, w2);
        acc4(sA2, c2); fma4(s12, c2, w2);
        acc4(sA0, d0); fma4(s10, d0, w3);
        acc4(sA1, d1); fma4(s11, d1, w3);
        acc4(sA2, d2); fma4(s12, d2, w3);
    }
    for (; r < rEnd; ++r) {
        const float w = tgt[r] ? 1.f : 0.f;
        const float4* ra = p + (size_t)r * D4;
        const float4 a0 = ra[0];
        const float4 a1 = ra[256];
        const float4 a2 = ra[512];
        acc4(sA0, a0); fma4(s10, a0, w);
        acc4(sA1, a1); fma4(s11, a1, w);
        acc4(sA2, a2); fma4(s12, a2, w);
    }

    // coalesced partial stores: [plane0|plane1] x 3072 floats
    float* base = partials + ((size_t)z * gyR + by) * (2 * 3072);
    float4* pl0 = reinterpret_cast<float4*>(base);
    float4* pl1 = reinterpret_cast<float4*>(base + 3072);
    pl0[tid]       = sA0; pl0[tid + 256] = sA1; pl0[tid + 512] = sA2;
    pl1[tid]       = s10; pl1[tid + 256] = s11; pl1[tid + 512] = s12;

    if (by == 0 && z == 0) do_stats(target, logdet, stats, N);
}

// generic fallback (any D): column-group blocks (correct, not tuned)
__global__ __launch_bounds__(BLOCK, 4) void k_colsum_gen(
    const float* __restrict__ mean,
    const float* __restrict__ log_sd,
    const int*   __restrict__ target,
    const float* __restrict__ logdet,
    float* __restrict__ partials,
    float* __restrict__ stats,
    int N, int D4, int Dp, int rowsPerBlk, int gyR)
{
    const int c4 = blockIdx.x * BLOCK + threadIdx.x;
    const bool colOK = (c4 < D4);
    const int rowBase = blockIdx.y * rowsPerBlk;
    int rEnd = rowsPerBlk;
    if (rowBase + rEnd > N) rEnd = N - rowBase;
    if (rEnd < 0) rEnd = 0;

    const float4* src4 =
        reinterpret_cast<const float4*>(blockIdx.z == 0 ? mean : log_sd);
    const float4* p   = src4 + (size_t)rowBase * D4 + (colOK ? c4 : 0);
    const int*    tgt = target + rowBase;

    float4 sA = make_float4(0.f,0.f,0.f,0.f);
    float4 s1 = make_float4(0.f,0.f,0.f,0.f);
    for (int r = 0; r < rEnd; ++r) {
        const float w = tgt[r] ? 1.f : 0.f;
        const float4 d = p[(size_t)r * D4];
        acc4(sA, d); fma4(s1, d, w);
    }

    if (colOK) {
        float* base = partials +
            ((size_t)blockIdx.z * gyR + blockIdx.y) * (2 * (size_t)Dp);
        reinterpret_cast<float4*>(base)[c4]      = sA;
        reinterpret_cast<float4*>(base + Dp)[c4] = s1;
    }
    if (blockIdx.x == 0 && blockIdx.y == 0 && blockIdx.z == 0)
        do_stats(target, logdet, stats, N);
}

// reduce partials over gyR (8 threads per output), finalize params + tables
__global__ __launch_bounds__(BLOCK) void k_reduce_finalize(
    const float* __restrict__ partials,
    float* __restrict__ ws,
    float* __restrict__ out,
    int D, int Dp, int gyR)
{
    const int sub  = threadIdx.x & 7;
    const int slot = threadIdx.x >> 3;                 // 0..31
    const int oidx = blockIdx.x * 32 + slot;           // [0, 2*D)
    const bool ok  = (oidx < 2 * D);
    const int cls = ok ? (oidx / D) : 0;
    const int col = ok ? (oidx - cls * D) : 0;

    const size_t strideBY = 2 * (size_t)Dp;
    const size_t zoff     = (size_t)gyR * strideBY;
    const int per = gyR >> 3;

    float mA = 0.f, m1 = 0.f, lA = 0.f, l1 = 0.f;
    for (int j = 0; j < per; ++j) {
        const size_t base = (size_t)(sub * per + j) * strideBY + col;
        mA += partials[base];
        m1 += partials[base + Dp];
        lA += partials[zoff + base];
        l1 += partials[zoff + base + Dp];
    }
    #pragma unroll
    for (int s = 1; s <= 4; s <<= 1) {
        mA += __shfl_xor(mA, s);
        m1 += __shfl_xor(m1, s);
        lA += __shfl_xor(lA, s);
        l1 += __shfl_xor(l1, s);
    }

    if (ok && sub == 0) {
        const float cnt = ws[4 + cls];
        const float m = (cls ? m1 : (mA - m1)) / cnt;
        const float l = (cls ? l1 : (lA - l1)) / cnt;
        out[1 + oidx]         = m;   // mus
        out[1 + 2 * D + oidx] = l;   // lsds
        float* p_tab = ws + 16;
        float* q_tab = p_tab + 2 * D;
        const float pv = 0.5f * expf(-2.f * l);
        p_tab[oidx] = pv;
        q_tab[oidx] = 2.f * pv * m;
    }
}

__global__ __launch_bounds__(BLOCK) void k_logp(
    const float* __restrict__ z,
    const int*   __restrict__ target,
    const float* __restrict__ ws,
    float* __restrict__ logp_out,
    int N, int D)
{
    const int wave = threadIdx.x >> 6;
    const int lane = threadIdx.x & 63;
    const int n    = blockIdx.x * 4 + wave;
    const int D4   = D >> 2;
    if (n >= N) return;

    const int t = __builtin_amdgcn_readfirstlane(target[n]);
    const float4* z4 = reinterpret_cast<const float4*>(z) + (size_t)n * D4;
    const float4* p4 = reinterpret_cast<const float4*>(ws + 16) + (size_t)t * D4;
    const float4* q4 = p4 + 2 * D4;

    float acc = 0.f;
    int i = lane;
    for (; i + 64 < D4; i += 128) {
        const float4 zz0 = z4[i];      const float4 zz1 = z4[i + 64];
        const float4 pp0 = p4[i];      const float4 pp1 = p4[i + 64];
        const float4 qq0 = q4[i];      const float4 qq1 = q4[i + 64];
        acc += zz0.x * (qq0.x - pp0.x * zz0.x);
        acc += zz0.y * (qq0.y - pp0.y * zz0.y);
        acc += zz0.z * (qq0.z - pp0.z * zz0.z);
        acc += zz0.w * (qq0.w - pp0.w * zz0.w);
        acc += zz1.x * (qq1.x - pp1.x * zz1.x);
        acc += zz1.y * (qq1.y - pp1.y * zz1.y);
        acc += zz1.z * (qq1.z - pp1.z * zz1.z);
        acc += zz1.w * (qq1.w - pp1.w * zz1.w);
    }
    for (; i < D4; i += 64) {
        const float4 zz = z4[i];
        const float4 pp = p4[i];
        const float4 qq = q4[i];
        acc += zz.x * (qq.x - pp.x * zz.x);
        acc += zz.y * (qq.y - pp.y * zz.y);
        acc += zz.z * (qq.z - pp.z * zz.z);
        acc += zz.w * (qq.w - pp.w * zz.w);
    }

    #pragma unroll
    for (int m = 32; m >= 1; m >>= 1) acc += __shfl_xor(acc, m);
    if (lane == 0) logp_out[n] = acc;        // Bc added in k_finalize2
}

// epilogue: per-class Bc from mus/lsds, patch logp, class means, prior
__global__ __launch_bounds__(1024) void k_finalize2(
    const int*   __restrict__ target,
    const float* __restrict__ stats,
    float* __restrict__ out,
    int N, int D, int out_off)
{
    const int tid = threadIdx.x;
    const float* mus  = out + 1;
    const float* lsds = out + 1 + 2 * D;
    float* logp = out + 1 + 4 * D;

    // phase 1: Bc[cls] = sum_d ( -0.5*log2pi - l - 0.5*exp(-2l)*m^2 )
    float b0 = 0.f, b1 = 0.f;
    for (int idx = tid; idx < 2 * D; idx += 1024) {
        const float m = mus[idx];
        const float l = lsds[idx];
        const float b = -0.5f * LOG_2PI_F - l - 0.5f * expf(-2.f * l) * m * m;
        if (idx < D) b0 += b; else b1 += b;
    }
    __shared__ float s0[1024];
    __shared__ float s1[1024];
    s0[tid] = b0; s1[tid] = b1;
    __syncthreads();
    for (int off = 512; off > 0; off >>= 1) {
        if (tid < off) {
            s0[tid] += s0[tid + off];
            s1[tid] += s1[tid + off];
        }
        __syncthreads();
    }
    const float B0 = s0[0];
    const float B1 = s1[0];
    __syncthreads();

    // phase 2: patch logp with Bc, accumulate per-class sums
    float cA = 0.f, c1 = 0.f;
    for (int i = tid; i < N; i += 1024) {
        const int   t = target[i];
        const float v = logp[i] + (t ? B1 : B0);
        logp[i] = v;
        cA += v;
        if (t) c1 += v;
    }
    s0[tid] = cA; s1[tid] = c1;
    __syncthreads();
    for (int off = 512; off > 0; off >>= 1) {
        if (tid < off) {
            s0[tid] += s0[tid + off];
            s1[tid] += s1[tid + off];
        }
        __syncthreads();
    }
    if (tid == 0) {
        const float lp0 = (s0[0] - s1[0]) / stats[4];
        const float lp1 = s1[0] / stats[5];
        const float ld0 = stats[2] / stats[4];
        const float ld1 = stats[3] / stats[5];
        out[out_off]     = lp0;            // log_p_total[0]
        out[out_off + 1] = lp1;            // log_p_total[1]
        out[0] = 0.5f * ((lp0 + ld0) + (lp1 + ld1));  // prior_logprob
    }
}

extern "C" void kernel_launch(void* const* d_in, const int* in_sizes, int n_in,
                              void* d_out, int out_size, void* d_ws, size_t ws_size,
                              hipStream_t stream)
{
    const float* z      = (const float*)d_in[0];
    const float* mean   = (const float*)d_in[1];
    const float* log_sd = (const float*)d_in[2];
    const float* logdet = (const float*)d_in[3];
    const int*   target = (const int*)d_in[4];
    float* out = (float*)d_out;
    float* ws  = (float*)d_ws;

    const int N  = in_sizes[3];            // 8192
    const int D  = in_sizes[0] / N;        // 3072
    const int D4 = D >> 2;                 // 768
    const int Dp = D4 * 4;                 // plane width (== D here)

    size_t part0 = (size_t)(16 + 4 * D);
    part0 = (part0 + 255) & ~(size_t)255;

    // pick gyR (power of 2, >= 8) so partials fit in ws
    int gyR = 512;
    while (gyR > 8 &&
           (part0 + (size_t)2 * gyR * 2 * Dp) * sizeof(float) > ws_size)
        gyR >>= 1;
    const int rowsPerBlk = (N + gyR - 1) / gyR;

    float* partials = ws + part0;

    // pass 1: streaming per-class column partial sums (+ stats in block 0)
    if (D4 == 768) {
        dim3 g1(gyR, 2);
        k_colsum3<<<g1, BLOCK, 0, stream>>>(mean, log_sd, target, logdet,
                                            partials, ws, N, rowsPerBlk, gyR);
    } else {
        dim3 g1((D4 + BLOCK - 1) / BLOCK, gyR, 2);
        k_colsum_gen<<<g1, BLOCK, 0, stream>>>(mean, log_sd, target, logdet,
                                               partials, ws, N, D4, Dp,
                                               rowsPerBlk, gyR);
    }

    // reduce partials + finalize class params + build p/q tables
    const int nred = (2 * D + 31) / 32;
    k_reduce_finalize<<<nred, BLOCK, 0, stream>>>(partials, ws, out, D, Dp, gyR);

    // pass 2: per-sample logp (one wave per row)
    float* logp_out = out + 1 + 4 * D;
    k_logp<<<(N + 3) / 4, BLOCK, 0, stream>>>(z, target, ws, logp_out, N, D);

    // epilogue: Bc + patch logp + class means + prior
    k_finalize2<<<1, 1024, 0, stream>>>(target, ws, out, N, D, 1 + 4 * D + N);
}

// Round 9
// 96.848 us; speedup vs baseline: 1.0152x; 1.0152x over previous
//
#include <hip/hip_runtime.h>

#define BLOCK 256
#define LOG_2PI_F 1.8378770664093453f

// ws layout (float offsets):
//   0..7   : stats: [2] ld_sum0 [3] ld_sum1 [4] cnt0 [5] cnt1
//   16     : p_tab [2*D]   (= 0.5*exp(-2*lsd))
//   16+2D  : q_tab [2*D]   (= 2*p*mu)
//   PART0  : partials [2(z)][gyR][2][Dp]   (plane 0 = sumAll, 1 = sumC1), Dp = D
//
// out layout: [0] prior | [1,1+2D) mus | [1+2D,1+4D) lsds |
//             [1+4D,1+4D+N) logp | [1+4D+N, +2) log_p_total

__device__ __forceinline__ void acc4(float4& s, const float4 d) {
    s.x += d.x; s.y += d.y; s.z += d.z; s.w += d.w;
}
__device__ __forceinline__ void fma4(float4& s, const float4 d, const float w) {
    s.x = fmaf(d.x, w, s.x); s.y = fmaf(d.y, w, s.y);
    s.z = fmaf(d.z, w, s.z); s.w = fmaf(d.w, w, s.w);
}

// forced-in-flight 16B global load: issue now, wait later
__device__ __forceinline__ float4 gload16(const float4* p) {
    float4 d;
    asm volatile("global_load_dwordx4 %0, %1, off" : "=v"(d) : "v"(p));
    return d;
}

// shared stats helper: counts + per-class logdet sums (run by one block)
__device__ void do_stats(const int* __restrict__ target,
                         const float* __restrict__ logdet,
                         float* __restrict__ stats, int N)
{
    const int tid = threadIdx.x;
    float ldA = 0.f, ld1 = 0.f;
    int   c1  = 0;
    if ((N & 3) == 0) {
        const int4*   t4 = reinterpret_cast<const int4*>(target);
        const float4* l4 = reinterpret_cast<const float4*>(logdet);
        for (int i = tid; i < (N >> 2); i += BLOCK) {
            const int4   t = t4[i];
            const float4 v = l4[i];
            ldA += v.x + v.y + v.z + v.w;
            if (t.x) { c1++; ld1 += v.x; }
            if (t.y) { c1++; ld1 += v.y; }
            if (t.z) { c1++; ld1 += v.z; }
            if (t.w) { c1++; ld1 += v.w; }
        }
    } else {
        for (int n = tid; n < N; n += BLOCK) {
            const float v = logdet[n];
            ldA += v;
            if (target[n]) { c1++; ld1 += v; }
        }
    }
    __shared__ float sB[BLOCK], sC[BLOCK];
    __shared__ int   sI[BLOCK];
    sB[tid] = ldA; sC[tid] = ld1; sI[tid] = c1;
    __syncthreads();
    for (int off = BLOCK / 2; off > 0; off >>= 1) {
        if (tid < off) {
            sB[tid] += sB[tid + off];
            sC[tid] += sC[tid + off];
            sI[tid] += sI[tid + off];
        }
        __syncthreads();
    }
    if (tid == 0) {
        stats[2] = sB[0] - sC[0];          // ld_sum0
        stats[3] = sC[0];                  // ld_sum1
        stats[4] = (float)(N - sI[0]);     // cnt0
        stats[5] = (float)sI[0];           // cnt1
    }
}

// fast path (D == 3072): ROUND-ROBIN rows — block by handles rows
// {by, by+gyR, by+2*gyR, ...}; consecutive blocks read consecutive rows,
// so the grid sweeps memory as one contiguous front (k_logp/m13 pattern).
__global__ __launch_bounds__(BLOCK, 4) void k_colsum3(
    const float* __restrict__ mean,
    const float* __restrict__ log_sd,
    const int*   __restrict__ target,
    const float* __restrict__ logdet,
    float* __restrict__ partials,
    float* __restrict__ stats,
    int N, int gyR)
{
    const int tid = threadIdx.x;
    const int by  = blockIdx.x;                 // 0..gyR-1
    const int z   = blockIdx.y;
    const int D4  = 768;                        // 3072 / 4

    const float4* src4 =
        reinterpret_cast<const float4*>(z == 0 ? mean : log_sd);
    const float4* p = src4 + (size_t)by * D4 + tid;   // row 'by' slice
    const size_t rstep = (size_t)gyR * D4;            // row stride (rows apart)

    const int nk = (by < N) ? ((N - 1 - by) / gyR + 1) : 0;   // rows this block

    float4 sA0 = make_float4(0.f,0.f,0.f,0.f);
    float4 sA1 = make_float4(0.f,0.f,0.f,0.f);
    float4 sA2 = make_float4(0.f,0.f,0.f,0.f);
    float4 s10 = make_float4(0.f,0.f,0.f,0.f);
    float4 s11 = make_float4(0.f,0.f,0.f,0.f);
    float4 s12 = make_float4(0.f,0.f,0.f,0.f);

    int k = 0;
    for (; k + 4 <= nk; k += 4) {
        const int rb = by + k * gyR;
        const float4* r0 = p + (size_t)k * rstep;
        const float4* r1 = r0 + rstep;
        const float4* r2 = r1 + rstep;
        const float4* r3 = r2 + rstep;
        // issue 12 independent 16B loads back-to-back
        const float4 a0 = gload16(r0);
        const float4 a1 = gload16(r0 + 256);
        const float4 a2 = gload16(r0 + 512);
        const float4 b0 = gload16(r1);
        const float4 b1 = gload16(r1 + 256);
        const float4 b2 = gload16(r1 + 512);
        const float4 c0 = gload16(r2);
        const float4 c1 = gload16(r2 + 256);
        const float4 c2 = gload16(r2 + 512);
        const float4 d0 = gload16(r3);
        const float4 d1 = gload16(r3 + 256);
        const float4 d2 = gload16(r3 + 512);
        asm volatile("s_waitcnt vmcnt(0)" ::: "memory");
        __builtin_amdgcn_sched_barrier(0);      // rule #18
        const float w0 = target[rb]            ? 1.f : 0.f;
        const float w1 = target[rb + gyR]      ? 1.f : 0.f;
        const float w2 = target[rb + 2 * gyR]  ? 1.f : 0.f;
        const float w3 = target[rb + 3 * gyR]  ? 1.f : 0.f;
        acc4(sA0, a0); fma4(s10, a0, w0);
        acc4(sA1, a1); fma4(s11, a1, w0);
        acc4(sA2, a2); fma4(s12, a2, w0);
        acc4(sA0, b0); fma4(s10, b0, w1);
        acc4(sA1, b1); fma4(s11, b1, w1);
        acc4(sA2, b2); fma4(s12, b2, w1);
        acc4(sA0, c0); fma4(s10, c0, w2);
        acc4(sA1, c1); fma4(s11, c1, w2);
        acc4(sA2, c2); fma4(s12, c2, w2);
        acc4(sA0, d0); fma4(s10, d0, w3);
        acc4(sA1, d1); fma4(s11, d1, w3);
        acc4(sA2, d2); fma4(s12, d2, w3);
    }
    for (; k < nk; ++k) {
        const float w = target[by + k * gyR] ? 1.f : 0.f;
        const float4* ra = p + (size_t)k * rstep;
        const float4 a0 = ra[0];
        const float4 a1 = ra[256];
        const float4 a2 = ra[512];
        acc4(sA0, a0); fma4(s10, a0, w);
        acc4(sA1, a1); fma4(s11, a1, w);
        acc4(sA2, a2); fma4(s12, a2, w);
    }

    // coalesced partial stores: [plane0|plane1] x 3072 floats
    float* base = partials + ((size_t)z * gyR + by) * (2 * 3072);
    float4* pl0 = reinterpret_cast<float4*>(base);
    float4* pl1 = reinterpret_cast<float4*>(base + 3072);
    pl0[tid]       = sA0; pl0[tid + 256] = sA1; pl0[tid + 512] = sA2;
    pl1[tid]       = s10; pl1[tid + 256] = s11; pl1[tid + 512] = s12;

    if (by == 0 && z == 0) do_stats(target, logdet, stats, N);
}

// generic fallback (any D): round-robin rows, column-group blocks
__global__ __launch_bounds__(BLOCK, 4) void k_colsum_gen(
    const float* __restrict__ mean,
    const float* __restrict__ log_sd,
    const int*   __restrict__ target,
    const float* __restrict__ logdet,
    float* __restrict__ partials,
    float* __restrict__ stats,
    int N, int D4, int Dp, int gyR)
{
    const int c4 = blockIdx.x * BLOCK + threadIdx.x;
    const bool colOK = (c4 < D4);
    const int by = blockIdx.y;

    const float4* src4 =
        reinterpret_cast<const float4*>(blockIdx.z == 0 ? mean : log_sd);
    const float4* p = src4 + (size_t)by * D4 + (colOK ? c4 : 0);
    const size_t rstep = (size_t)gyR * D4;
    const int nk = (by < N) ? ((N - 1 - by) / gyR + 1) : 0;

    float4 sA = make_float4(0.f,0.f,0.f,0.f);
    float4 s1 = make_float4(0.f,0.f,0.f,0.f);
    for (int k = 0; k < nk; ++k) {
        const float w = target[by + k * gyR] ? 1.f : 0.f;
        const float4 d = p[(size_t)k * rstep];
        acc4(sA, d); fma4(s1, d, w);
    }

    if (colOK) {
        float* base = partials +
            ((size_t)blockIdx.z * gyR + by) * (2 * (size_t)Dp);
        reinterpret_cast<float4*>(base)[c4]      = sA;
        reinterpret_cast<float4*>(base + Dp)[c4] = s1;
    }
    if (blockIdx.x == 0 && by == 0 && blockIdx.z == 0)
        do_stats(target, logdet, stats, N);
}

// reduce partials over gyR (8 threads per output), finalize params + tables
__global__ __launch_bounds__(BLOCK) void k_reduce_finalize(
    const float* __restrict__ partials,
    float* __restrict__ ws,
    float* __restrict__ out,
    int D, int Dp, int gyR)
{
    const int sub  = threadIdx.x & 7;
    const int slot = threadIdx.x >> 3;                 // 0..31
    const int oidx = blockIdx.x * 32 + slot;           // [0, 2*D)
    const bool ok  = (oidx < 2 * D);
    const int cls = ok ? (oidx / D) : 0;
    const int col = ok ? (oidx - cls * D) : 0;

    const size_t strideBY = 2 * (size_t)Dp;
    const size_t zoff     = (size_t)gyR * strideBY;
    const int per = gyR >> 3;

    float mA = 0.f, m1 = 0.f, lA = 0.f, l1 = 0.f;
    for (int j = 0; j < per; ++j) {
        const size_t base = (size_t)(sub * per + j) * strideBY + col;
        mA += partials[base];
        m1 += partials[base + Dp];
        lA += partials[zoff + base];
        l1 += partials[zoff + base + Dp];
    }
    #pragma unroll
    for (int s = 1; s <= 4; s <<= 1) {
        mA += __shfl_xor(mA, s);
        m1 += __shfl_xor(m1, s);
        lA += __shfl_xor(lA, s);
        l1 += __shfl_xor(l1, s);
    }

    if (ok && sub == 0) {
        const float cnt = ws[4 + cls];
        const float m = (cls ? m1 : (mA - m1)) / cnt;
        const float l = (cls ? l1 : (lA - l1)) / cnt;
        out[1 + oidx]         = m;   // mus
        out[1 + 2 * D + oidx] = l;   // lsds
        float* p_tab = ws + 16;
        float* q_tab = p_tab + 2 * D;
        const float pv = 0.5f * expf(-2.f * l);
        p_tab[oidx] = pv;
        q_tab[oidx] = 2.f * pv * m;
    }
}

__global__ __launch_bounds__(BLOCK) void k_logp(
    const float* __restrict__ z,
    const int*   __restrict__ target,
    const float* __restrict__ ws,
    float* __restrict__ logp_out,
    int N, int D)
{
    const int wave = threadIdx.x >> 6;
    const int lane = threadIdx.x & 63;
    const int n    = blockIdx.x * 4 + wave;
    const int D4   = D >> 2;
    if (n >= N) return;

    const int t = __builtin_amdgcn_readfirstlane(target[n]);
    const float4* z4 = reinterpret_cast<const float4*>(z) + (size_t)n * D4;
    const float4* p4 = reinterpret_cast<const float4*>(ws + 16) + (size_t)t * D4;
    const float4* q4 = p4 + 2 * D4;

    float acc = 0.f;
    int i = lane;
    for (; i + 64 < D4; i += 128) {
        const float4 zz0 = z4[i];      const float4 zz1 = z4[i + 64];
        const float4 pp0 = p4[i];      const float4 pp1 = p4[i + 64];
        const float4 qq0 = q4[i];      const float4 qq1 = q4[i + 64];
        acc += zz0.x * (qq0.x - pp0.x * zz0.x);
        acc += zz0.y * (qq0.y - pp0.y * zz0.y);
        acc += zz0.z * (qq0.z - pp0.z * zz0.z);
        acc += zz0.w * (qq0.w - pp0.w * zz0.w);
        acc += zz1.x * (qq1.x - pp1.x * zz1.x);
        acc += zz1.y * (qq1.y - pp1.y * zz1.y);
        acc += zz1.z * (qq1.z - pp1.z * zz1.z);
        acc += zz1.w * (qq1.w - pp1.w * zz1.w);
    }
    for (; i < D4; i += 64) {
        const float4 zz = z4[i];
        const float4 pp = p4[i];
        const float4 qq = q4[i];
        acc += zz.x * (qq.x - pp.x * zz.x);
        acc += zz.y * (qq.y - pp.y * zz.y);
        acc += zz.z * (qq.z - pp.z * zz.z);
        acc += zz.w * (qq.w - pp.w * zz.w);
    }

    #pragma unroll
    for (int m = 32; m >= 1; m >>= 1) acc += __shfl_xor(acc, m);
    if (lane == 0) logp_out[n] = acc;        // Bc added in k_finalize2
}

// epilogue: per-class Bc from mus/lsds, patch logp, class means, prior
__global__ __launch_bounds__(1024) void k_finalize2(
    const int*   __restrict__ target,
    const float* __restrict__ stats,
    float* __restrict__ out,
    int N, int D, int out_off)
{
    const int tid = threadIdx.x;
    const float* mus  = out + 1;
    const float* lsds = out + 1 + 2 * D;
    float* logp = out + 1 + 4 * D;

    // phase 1: Bc[cls] = sum_d ( -0.5*log2pi - l - 0.5*exp(-2l)*m^2 )
    float b0 = 0.f, b1 = 0.f;
    for (int idx = tid; idx < 2 * D; idx += 1024) {
        const float m = mus[idx];
        const float l = lsds[idx];
        const float b = -0.5f * LOG_2PI_F - l - 0.5f * expf(-2.f * l) * m * m;
        if (idx < D) b0 += b; else b1 += b;
    }
    __shared__ float s0[1024];
    __shared__ float s1[1024];
    s0[tid] = b0; s1[tid] = b1;
    __syncthreads();
    for (int off = 512; off > 0; off >>= 1) {
        if (tid < off) {
            s0[tid] += s0[tid + off];
            s1[tid] += s1[tid + off];
        }
        __syncthreads();
    }
    const float B0 = s0[0];
    const float B1 = s1[0];
    __syncthreads();

    // phase 2: patch logp with Bc, accumulate per-class sums
    float cA = 0.f, c1 = 0.f;
    for (int i = tid; i < N; i += 1024) {
        const int   t = target[i];
        const float v = logp[i] + (t ? B1 : B0);
        logp[i] = v;
        cA += v;
        if (t) c1 += v;
    }
    s0[tid] = cA; s1[tid] = c1;
    __syncthreads();
    for (int off = 512; off > 0; off >>= 1) {
        if (tid < off) {
            s0[tid] += s0[tid + off];
            s1[tid] += s1[tid + off];
        }
        __syncthreads();
    }
    if (tid == 0) {
        const float lp0 = (s0[0] - s1[0]) / stats[4];
        const float lp1 = s1[0] / stats[5];
        const float ld0 = stats[2] / stats[4];
        const float ld1 = stats[3] / stats[5];
        out[out_off]     = lp0;            // log_p_total[0]
        out[out_off + 1] = lp1;            // log_p_total[1]
        out[0] = 0.5f * ((lp0 + ld0) + (lp1 + ld1));  // prior_logprob
    }
}

extern "C" void kernel_launch(void* const* d_in, const int* in_sizes, int n_in,
                              void* d_out, int out_size, void* d_ws, size_t ws_size,
                              hipStream_t stream)
{
    const float* z      = (const float*)d_in[0];
    const float* mean   = (const float*)d_in[1];
    const float* log_sd = (const float*)d_in[2];
    const float* logdet = (const float*)d_in[3];
    const int*   target = (const int*)d_in[4];
    float* out = (float*)d_out;
    float* ws  = (float*)d_ws;

    const int N  = in_sizes[3];            // 8192
    const int D  = in_sizes[0] / N;        // 3072
    const int D4 = D >> 2;                 // 768
    const int Dp = D4 * 4;                 // plane width (== D here)

    size_t part0 = (size_t)(16 + 4 * D);
    part0 = (part0 + 255) & ~(size_t)255;

    // pick gyR (power of 2, >= 8) so partials fit in ws
    int gyR = 512;
    while (gyR > 8 &&
           (part0 + (size_t)2 * gyR * 2 * Dp) * sizeof(float) > ws_size)
        gyR >>= 1;

    float* partials = ws + part0;

    // pass 1: round-robin-row per-class column partial sums (+ stats in blk 0)
    if (D4 == 768) {
        dim3 g1(gyR, 2);
        k_colsum3<<<g1, BLOCK, 0, stream>>>(mean, log_sd, target, logdet,
                                            partials, ws, N, gyR);
    } else {
        dim3 g1((D4 + BLOCK - 1) / BLOCK, gyR, 2);
        k_colsum_gen<<<g1, BLOCK, 0, stream>>>(mean, log_sd, target, logdet,
                                               partials, ws, N, D4, Dp, gyR);
    }

    // reduce partials + finalize class params + build p/q tables
    const int nred = (2 * D + 31) / 32;
    k_reduce_finalize<<<nred, BLOCK, 0, stream>>>(partials, ws, out, D, Dp, gyR);

    // pass 2: per-sample logp (one wave per row)
    float* logp_out = out + 1 + 4 * D;
    k_logp<<<(N + 3) / 4, BLOCK, 0, stream>>>(z, target, ws, logp_out, N, D);

    // epilogue: Bc + patch logp + class means + prior
    k_finalize2<<<1, 1024, 0, stream>>>(target, ws, out, N, D, 1 + 4 * D + N);
}